// Round 1
// baseline (2386.332 us; speedup 1.0000x reference)
//
#include <hip/hip_runtime.h>

// 4D conv, SAME (P=1), K=3 per dim.
// x:   (2, 16, 24, 24, 24, 24) fp32
// W:   (32, 16, 3, 3, 3, 3)    fp32
// out: (2, 32, 24, 24, 24, 24) fp32
//
// Block = (b, d0, d1, co_group of 4). 576 threads cover the 24x24 (d2,d3)
// plane. Loop over (ci,k0,k1): stage 26x26 padded slab in LDS, 36 FMAs/thread.

#define D      24
#define D2_    (24*24)
#define D3_    (24*24*24)
#define D4_    (24*24*24*24)
#define DP     26
#define CIN    16
#define COUT   32
#define WCO    1296   // 16*81, W stride per co

__global__ __launch_bounds__(576) void conv4d_f32_kernel(
    const float* __restrict__ x,
    const float* __restrict__ W,
    float* __restrict__ out)
{
    const int cog = blockIdx.x;        // 0..7  -> co = 4*cog..4*cog+3
    const int d01 = blockIdx.y;        // 0..575
    const int b   = blockIdx.z;        // 0..1
    const int d0  = d01 / D;
    const int d1  = d01 % D;
    const int tid = threadIdx.x;       // 0..575
    const int d2  = tid / D;
    const int d3  = tid % D;
    const int co0 = cog * 4;

    __shared__ float slab[DP * DP];

    float acc0 = 0.f, acc1 = 0.f, acc2 = 0.f, acc3 = 0.f;

    const float* xb = x + (long)b * CIN * D4_;

    for (int ci = 0; ci < CIN; ++ci) {
        const float* xc = xb + (long)ci * D4_;
        for (int k0 = 0; k0 < 3; ++k0) {
            const int r0 = d0 + k0 - 1;
            if ((unsigned)r0 >= (unsigned)D) continue;      // block-uniform skip
            for (int k1 = 0; k1 < 3; ++k1) {
                const int r1 = d1 + k1 - 1;
                if ((unsigned)r1 >= (unsigned)D) continue;  // block-uniform skip

                // ---- stage 26x26 zero-padded slab into LDS ----
                const float* xp = xc + (long)r0 * D3_ + (long)r1 * D2_;
                for (int i = tid; i < DP * DP; i += 576) {
                    const int e2 = i / DP;
                    const int e3 = i - e2 * DP;
                    const int s2 = e2 - 1;
                    const int s3 = e3 - 1;
                    float v = 0.f;
                    if ((unsigned)s2 < (unsigned)D && (unsigned)s3 < (unsigned)D)
                        v = xp[s2 * D + s3];
                    slab[i] = v;
                }
                __syncthreads();

                // ---- weights for this (ci,k0,k1): block-uniform -> SGPRs ----
                const float* wp = W + ci * 81 + k0 * 27 + k1 * 9;
                float w0[9], w1[9], w2[9], w3[9];
                #pragma unroll
                for (int j = 0; j < 9; ++j) {
                    w0[j] = wp[(co0 + 0) * WCO + j];
                    w1[j] = wp[(co0 + 1) * WCO + j];
                    w2[j] = wp[(co0 + 2) * WCO + j];
                    w3[j] = wp[(co0 + 3) * WCO + j];
                }

                // ---- 3x3 inner window, 4 output channels ----
                #pragma unroll
                for (int k2 = 0; k2 < 3; ++k2) {
                    #pragma unroll
                    for (int k3 = 0; k3 < 3; ++k3) {
                        const float v = slab[(d2 + k2) * DP + (d3 + k3)];
                        const int j = k2 * 3 + k3;
                        acc0 += v * w0[j];
                        acc1 += v * w1[j];
                        acc2 += v * w2[j];
                        acc3 += v * w3[j];
                    }
                }
                __syncthreads();
            }
        }
    }

    const long obase = ((long)b * COUT + co0) * D4_
                     + (long)d0 * D3_ + (long)d1 * D2_ + d2 * D + d3;
    out[obase]            = acc0;
    out[obase + 1L * D4_] = acc1;
    out[obase + 2L * D4_] = acc2;
    out[obase + 3L * D4_] = acc3;
}

extern "C" void kernel_launch(void* const* d_in, const int* in_sizes, int n_in,
                              void* d_out, int out_size, void* d_ws, size_t ws_size,
                              hipStream_t stream)
{
    const float* x = (const float*)d_in[0];
    const float* W = (const float*)d_in[1];
    float* out     = (float*)d_out;

    dim3 grid(COUT / 4, D * D, 2);   // (co groups, d0*d1, b)
    dim3 block(576);
    hipLaunchKernelGGL(conv4d_f32_kernel, grid, block, 0, stream, x, W, out);
}

// Round 4
// 263.901 us; speedup vs baseline: 9.0425x; 9.0425x over previous
//
#include <hip/hip_runtime.h>

// 4D conv (K=3^4, SAME P=1) as implicit GEMM on bf16 MFMA — SINGLE kernel.
// x:   (2, 16, 24,24,24,24) fp32
// W:   (32, 16, 3,3,3,3)    fp32
// out: (2, 32, 24,24,24,24) fp32
//
// C[co=32][pos=576] per block (b,d0,d1); K-step = 16 ci per tap, 81 taps.
// Per (k0,k1) body: stage 26x26x16 x-slab (bf16, ci innermost) AND the
// 9-tap weight group agrp[9][co][ci] (bf16, XOR-swizzled fragments) into
// LDS, then 9 taps x 3 N-tiles of v_mfma_f32_32x32x16_bf16.
//
// No d_ws, no second kernel: the R3 failure was post-timing divergence from
// a cross-kernel RAW through d_ws under graph replay (per-XCD L2 dirty
// lines not written back between graph nodes). Reading the immutable W
// input directly removes the hazard.

#define D      24
#define D2_    (24*24)
#define D3_    (24*24*24)
#define D4_    (24*24*24*24)
#define CIN    16
#define COUT   32
#define DP     26
#define TPW    3          // N-tiles (32 pos) per wave; 6 waves * 3 * 32 = 576
#define NTHR   384

typedef __bf16 bf16x8 __attribute__((ext_vector_type(8)));
typedef float  f32x16 __attribute__((ext_vector_type(16)));
typedef unsigned short ushort_t;
typedef ushort_t ushort8 __attribute__((ext_vector_type(8)));
typedef ushort_t ushort4_ __attribute__((ext_vector_type(4)));

union u2b8 { ushort8 u; bf16x8 b; };

__device__ inline ushort_t f2bf(float f) {
    union { float f; unsigned u; } x; x.f = f;
    unsigned r = x.u + 0x7FFFu + ((x.u >> 16) & 1u);   // round-nearest-even
    return (ushort_t)(r >> 16);
}

// fragment-id swizzle: spreads stride-32B b128 reads across banks
__device__ inline int fswz(int f) { return f ^ ((f >> 3) & 7); }

__global__ __launch_bounds__(NTHR) void conv4d_mfma(
    const float* __restrict__ x,
    const float* __restrict__ W,
    float* __restrict__ out)
{
    __shared__ __align__(16) ushort_t slab[DP * DP * CIN];   // 21632 B
    __shared__ __align__(16) ushort_t agrp[9 * COUT * CIN];  //  9216 B

    const int d01  = blockIdx.x;
    const int b    = blockIdx.y;
    const int d0   = d01 / D;
    const int d1   = d01 % D;
    const int tid  = threadIdx.x;
    const int lane = tid & 63;
    const int wave = tid >> 6;
    const int col  = lane & 31;
    const int hi   = lane >> 5;

    // per-lane constants
    const int afbase = fswz(col * 2 + hi) * 8;   // agrp ushort offset (+kc*512)
    int ppos[TPW];
    int sbase[TPW];
    #pragma unroll
    for (int t = 0; t < TPW; ++t) {
        int pos = (wave * TPW + t) * 32 + col;
        int d2  = pos / D;
        int d3  = pos - d2 * D;
        ppos[t]  = pos;
        sbase[t] = (d2 * DP + d3) * CIN + hi * 8;
    }

    f32x16 acc[TPW];
    #pragma unroll
    for (int t = 0; t < TPW; ++t)
        #pragma unroll
        for (int r = 0; r < 16; ++r) acc[t][r] = 0.f;

    const float* xb = x + (long)b * CIN * D4_;

    for (int k0 = 0; k0 < 3; ++k0) {
        const int r0 = d0 + k0 - 1;
        if ((unsigned)r0 >= (unsigned)D) continue;          // block-uniform
        for (int k1 = 0; k1 < 3; ++k1) {
            const int r1 = d1 + k1 - 1;
            if ((unsigned)r1 >= (unsigned)D) continue;      // block-uniform

            __syncthreads();   // previous body's compute done before overwrite

            // ---- stage x-slab: [p2*26+p3][ci] bf16, zero-padded ----
            const float* xp = xb + (long)r0 * D3_ + (long)r1 * D2_;
            for (int idx = tid; idx < DP * DP * 2; idx += NTHR) {
                const int pidx = idx >> 1;
                const int h    = idx & 1;
                const int p2   = pidx / DP;
                const int p3   = pidx - p2 * DP;
                const int s2   = p2 - 1;
                const int s3   = p3 - 1;
                const bool in  = (unsigned)s2 < (unsigned)D &&
                                 (unsigned)s3 < (unsigned)D;
                const float* xs = xp + s2 * D + s3;
                ushort8 v;
                #pragma unroll
                for (int c = 0; c < 8; ++c) {
                    float f = in ? xs[(long)(h * 8 + c) * D4_] : 0.f;
                    v[c] = f2bf(f);
                }
                *(ushort8*)&slab[idx * 8] = v;
            }

            // ---- stage weight group: agrp[tap][frag f=co*2+hi swizzled] ----
            // unit = (tap, co, q): 4 ci values (ci = (q>>1)*8 + (q&1)*4 + c)
            const int kw0 = k0 * 27 + k1 * 9;
            for (int u = tid; u < 9 * COUT * 4; u += NTHR) {   // 1152 units
                const int tap = u >> 7;
                const int rem = u & 127;
                const int co  = rem >> 2;
                const int q   = rem & 3;
                const int ci0 = (q >> 1) * 8 + (q & 1) * 4;
                const float* wp = W + co * (CIN * 81) + kw0 + tap;
                ushort4_ v;
                #pragma unroll
                for (int c = 0; c < 4; ++c)
                    v[c] = f2bf(wp[(ci0 + c) * 81]);
                const int f  = co * 2 + (q >> 1);
                const int h2 = q & 1;
                *(ushort4_*)&agrp[tap * 512 + fswz(f) * 8 + h2 * 4] = v;
            }
            __syncthreads();

            // ---- A fragments from LDS (swizzled b128 reads) ----
            bf16x8 af[9];
            #pragma unroll
            for (int kc = 0; kc < 9; ++kc) {
                u2b8 cvt;
                cvt.u = *(const ushort8*)&agrp[kc * 512 + afbase];
                af[kc] = cvt.b;
            }

            // ---- 9 taps x TPW N-tiles of MFMA ----
            #pragma unroll
            for (int kc = 0; kc < 9; ++kc) {
                const int k2 = kc / 3, k3 = kc - 3 * (kc / 3);
                const int koff = (k2 * DP + k3) * CIN;      // compile-time
                #pragma unroll
                for (int t = 0; t < TPW; ++t) {
                    u2b8 cvt;
                    cvt.u = *(const ushort8*)&slab[sbase[t] + koff];
                    acc[t] = __builtin_amdgcn_mfma_f32_32x32x16_bf16(
                                 af[kc], cvt.b, acc[t], 0, 0, 0);
                }
            }
        }
    }

    // ---- epilogue: C[row=co][col=pos]; row=(r&3)+8*(r>>2)+4*hi ----
    float* ob = out + (long)b * COUT * D4_ + (long)d0 * D3_ + (long)d1 * D2_;
    #pragma unroll
    for (int t = 0; t < TPW; ++t) {
        #pragma unroll
        for (int r = 0; r < 16; ++r) {
            const int co = (r & 3) + 8 * (r >> 2) + 4 * hi;
            ob[(long)co * D4_ + ppos[t]] = acc[t][r];
        }
    }
}

extern "C" void kernel_launch(void* const* d_in, const int* in_sizes, int n_in,
                              void* d_out, int out_size, void* d_ws, size_t ws_size,
                              hipStream_t stream)
{
    const float* x = (const float*)d_in[0];
    const float* W = (const float*)d_in[1];
    float* out     = (float*)d_out;

    hipLaunchKernelGGL(conv4d_mfma, dim3(D * D, 2), dim3(NTHR), 0, stream,
                       x, W, out);
}

// Round 5
// 177.927 us; speedup vs baseline: 13.4118x; 1.4832x over previous
//
#include <hip/hip_runtime.h>

// 4D conv (K=3^4, SAME P=1), bf16 MFMA implicit GEMM, ONE fused kernel:
//   phase 1: transpose+convert x -> xt[b][d0][p1(26)][p2(26)][p3(26)][ci(16)] bf16
//            (pad baked into p1,p2,p3) and W -> Wt[81][co][ci] bf16, in d_ws.
//   software grid barrier (device-scope atomics; counter reset each call via
//   captured hipMemsetAsync; grid=256 -> >=1 block/CU at any VGPR/LDS => no deadlock)
//   phase 2: per tile (b,d0,d1): bodies (k0 valid)x(k1 0..2); slab stage is a
//            CONTIGUOUS 21632B global_load_lds copy (double-buffered, issued
//            right after the barrier -> latency hidden); 27 MFMA/body/wave.
// Fallback: if ws_size too small, launch the proven R4 single-kernel path.

#define D      24
#define D2_    (24*24)
#define D3_    (24*24*24)
#define D4_    (24*24*24*24)
#define CIN    16
#define COUT   32
#define DP     26
#define TPW    3
#define NTHR   384
#define GRID   256
#define NTILES (2*24*24)

#define XT_ELEMS  (2*24*26*26*26*16)        // 13,498,368 bf16
#define XT_BYTES  (XT_ELEMS*2)              // 26,996,736 B
#define WT_ELEMS  (81*32*16)                // 41,472 bf16
#define CNT_OFF_B (XT_BYTES + WT_ELEMS*2)   // 27,079,680
#define WS_NEED   (CNT_OFF_B + 64)

typedef __bf16 bf16x8 __attribute__((ext_vector_type(8)));
typedef float  f32x16 __attribute__((ext_vector_type(16)));
typedef unsigned short ushort_t;
typedef ushort_t ushort8 __attribute__((ext_vector_type(8)));
typedef ushort_t ushort4_ __attribute__((ext_vector_type(4)));

union u2b8 { ushort8 u; bf16x8 b; };

typedef const __attribute__((address_space(1))) unsigned int gu32;
typedef __attribute__((address_space(3))) unsigned int lu32;

__device__ inline ushort_t f2bf(float f) {
    union { float f; unsigned u; } x; x.f = f;
    unsigned r = x.u + 0x7FFFu + ((x.u >> 16) & 1u);   // RNE
    return (ushort_t)(r >> 16);
}

// ============================ fused kernel ============================
__global__ __launch_bounds__(NTHR) void conv4d_fused(
    const float* __restrict__ x,
    const float* __restrict__ W,
    float* __restrict__ out,
    ushort_t* __restrict__ ws)
{
    __shared__ __align__(16) ushort_t slab[2][DP * DP * CIN];  // 2 x 21632 B

    ushort_t* xt = ws;
    ushort_t* Wt = ws + XT_BYTES / 2;
    unsigned* cnt = (unsigned*)((char*)ws + CNT_OFF_B);

    const int bk  = blockIdx.x;
    const int tid = threadIdx.x;

    // ---------------- phase 1: transpose/convert ----------------
    {
        const long gtid = (long)bk * NTHR + tid;
        const long nthr = (long)GRID * NTHR;
        for (long u = gtid; u < XT_ELEMS / 8; u += nthr) {
            const int  h   = (int)(u & 1);
            long pos = u >> 1;
            const int p3 = (int)(pos % 26); pos /= 26;
            const int p2 = (int)(pos % 26); pos /= 26;
            const int p1 = (int)(pos % 26); pos /= 26;
            const int d0 = (int)(pos % 24);
            const int b  = (int)(pos / 24);
            const int r1 = p1 - 1, r2 = p2 - 1, r3 = p3 - 1;
            ushort8 v;
            if ((unsigned)r1 < 24u && (unsigned)r2 < 24u && (unsigned)r3 < 24u) {
                const float* xp = x + (long)(b * 16 + h * 8) * D4_
                                    + d0 * D3_ + r1 * D2_ + r2 * D + r3;
                #pragma unroll
                for (int c = 0; c < 8; ++c) v[c] = f2bf(xp[(long)c * D4_]);
            } else {
                #pragma unroll
                for (int c = 0; c < 8; ++c) v[c] = 0;
            }
            *(ushort8*)&xt[u * 8] = v;
        }
        for (long i = gtid; i < WT_ELEMS; i += nthr) {
            const int tap = (int)(i >> 9);
            const int co  = (int)((i >> 4) & 31);
            const int ci  = (int)(i & 15);
            Wt[i] = f2bf(W[((long)co * 16 + ci) * 81 + tap]);
        }
    }

    // ---------------- grid barrier (device scope) ----------------
    __threadfence();
    __syncthreads();
    if (tid == 0) {
        __hip_atomic_fetch_add(cnt, 1u, __ATOMIC_ACQ_REL, __HIP_MEMORY_SCOPE_AGENT);
        while (__hip_atomic_load(cnt, __ATOMIC_ACQUIRE, __HIP_MEMORY_SCOPE_AGENT)
               < (unsigned)GRID)
            __builtin_amdgcn_s_sleep(2);
    }
    __syncthreads();

    // ---------------- phase 2: implicit GEMM ----------------
    const int lane = tid & 63;
    const int wave = tid >> 6;
    const int col  = lane & 31;
    const int hi   = lane >> 5;

    int ppos[TPW], sbase[TPW];
    #pragma unroll
    for (int t = 0; t < TPW; ++t) {
        const int pos = (wave * TPW + t) * 32 + col;
        const int d2  = pos / D;
        const int d3  = pos - d2 * D;
        ppos[t]  = pos;
        sbase[t] = (d2 * DP + d3) * CIN + hi * 8;
    }

    int buf = 0;
    for (int tile = bk; tile < NTILES; tile += GRID) {
        const int b   = tile / 576;
        const int d01 = tile % 576;
        const int d0  = d01 / 24;
        const int d1  = d01 % 24;

        f32x16 acc[TPW];
        #pragma unroll
        for (int t = 0; t < TPW; ++t)
            #pragma unroll
            for (int r = 0; r < 16; ++r) acc[t][r] = 0.f;

        const int k0lo = (d0 == 0) ? 1 : 0;
        const int k0hi = (d0 == 23) ? 1 : 2;
        const int nb   = (k0hi - k0lo + 1) * 3;

        // stage body i into slab[sb]
        auto stage = [&](int sb, int i) {
            const int k0 = k0lo + i / 3;
            const int k1 = i % 3;
            const int r0 = d0 + k0 - 1;                 // 0..23 by construction
            const ushort_t* src = xt + (((long)b * 24 + r0) * 26 + (d1 + k1))
                                       * (676 * 16);
            ushort_t* dst = &slab[sb][0];
            for (int c = wave; c < 22; c += 6) {
                const bool act = (c < 21) | (lane < 8);  // tail chunk = 128 B
                if (act)
                    __builtin_amdgcn_global_load_lds(
                        (gu32*)(src) + (c * 256 + lane * 4),
                        (lu32*)(dst + c * 512), 16, 0, 0);
            }
        };

        __syncthreads();            // prev tile's readers done before overwrite
        stage(buf, 0);

        for (int i = 0; i < nb; ++i) {
            __syncthreads();        // slab[buf] landed; prev compute done
            if (i + 1 < nb) stage(buf ^ 1, i + 1);

            const int k0 = k0lo + i / 3;
            const int k1 = i % 3;
            const int tapg = (k0 * 3 + k1) * 9;

            bf16x8 af[9];
            #pragma unroll
            for (int kc = 0; kc < 9; ++kc) {
                u2b8 cvt;
                cvt.u = *(const ushort8*)&Wt[((long)(tapg + kc) * 32 + col) * 16
                                             + hi * 8];
                af[kc] = cvt.b;
            }

            #pragma unroll
            for (int kc = 0; kc < 9; ++kc) {
                const int k2 = kc / 3, k3 = kc - 3 * (kc / 3);
                const int koff = (k2 * DP + k3) * CIN;   // compile-time
                #pragma unroll
                for (int t = 0; t < TPW; ++t) {
                    u2b8 cvt;
                    cvt.u = *(const ushort8*)&slab[buf][sbase[t] + koff];
                    acc[t] = __builtin_amdgcn_mfma_f32_32x32x16_bf16(
                                 af[kc], cvt.b, acc[t], 0, 0, 0);
                }
            }
            buf ^= 1;
        }

        // epilogue: row=co=(r&3)+8*(r>>2)+4*hi, col=pos
        float* ob = out + (long)b * COUT * D4_ + (long)d0 * D3_ + (long)d1 * D2_;
        #pragma unroll
        for (int t = 0; t < TPW; ++t) {
            #pragma unroll
            for (int r = 0; r < 16; ++r) {
                const int co = (r & 3) + 8 * (r >> 2) + 4 * hi;
                ob[(long)co * D4_ + ppos[t]] = acc[t][r];
            }
        }
    }
}

// ===================== fallback: proven R4 kernel =====================
__device__ inline int fswz(int f) { return f ^ ((f >> 3) & 7); }

__global__ __launch_bounds__(NTHR) void conv4d_mfma_fb(
    const float* __restrict__ x,
    const float* __restrict__ W,
    float* __restrict__ out)
{
    __shared__ __align__(16) ushort_t slab[DP * DP * CIN];
    __shared__ __align__(16) ushort_t agrp[9 * COUT * CIN];

    const int d01  = blockIdx.x;
    const int b    = blockIdx.y;
    const int d0   = d01 / D;
    const int d1   = d01 % D;
    const int tid  = threadIdx.x;
    const int lane = tid & 63;
    const int wave = tid >> 6;
    const int col  = lane & 31;
    const int hi   = lane >> 5;

    const int afbase = fswz(col * 2 + hi) * 8;
    int ppos[TPW], sbase[TPW];
    #pragma unroll
    for (int t = 0; t < TPW; ++t) {
        int pos = (wave * TPW + t) * 32 + col;
        int d2  = pos / D;
        int d3  = pos - d2 * D;
        ppos[t]  = pos;
        sbase[t] = (d2 * DP + d3) * CIN + hi * 8;
    }

    f32x16 acc[TPW];
    #pragma unroll
    for (int t = 0; t < TPW; ++t)
        #pragma unroll
        for (int r = 0; r < 16; ++r) acc[t][r] = 0.f;

    const float* xb = x + (long)b * CIN * D4_;

    for (int k0 = 0; k0 < 3; ++k0) {
        const int r0 = d0 + k0 - 1;
        if ((unsigned)r0 >= (unsigned)D) continue;
        for (int k1 = 0; k1 < 3; ++k1) {
            const int r1 = d1 + k1 - 1;
            if ((unsigned)r1 >= (unsigned)D) continue;

            __syncthreads();

            const float* xp = xb + (long)r0 * D3_ + (long)r1 * D2_;
            for (int idx = tid; idx < DP * DP * 2; idx += NTHR) {
                const int pidx = idx >> 1;
                const int h    = idx & 1;
                const int p2   = pidx / DP;
                const int p3   = pidx - p2 * DP;
                const int s2   = p2 - 1;
                const int s3   = p3 - 1;
                const bool in  = (unsigned)s2 < (unsigned)D &&
                                 (unsigned)s3 < (unsigned)D;
                const float* xs = xp + s2 * D + s3;
                ushort8 v;
                #pragma unroll
                for (int c = 0; c < 8; ++c) {
                    float f = in ? xs[(long)(h * 8 + c) * D4_] : 0.f;
                    v[c] = f2bf(f);
                }
                *(ushort8*)&slab[idx * 8] = v;
            }

            const int kw0 = k0 * 27 + k1 * 9;
            for (int u = tid; u < 9 * COUT * 4; u += NTHR) {
                const int tap = u >> 7;
                const int rem = u & 127;
                const int co  = rem >> 2;
                const int q   = rem & 3;
                const int ci0 = (q >> 1) * 8 + (q & 1) * 4;
                const float* wp = W + co * (CIN * 81) + kw0 + tap;
                ushort4_ v;
                #pragma unroll
                for (int c = 0; c < 4; ++c)
                    v[c] = f2bf(wp[(ci0 + c) * 81]);
                const int f  = co * 2 + (q >> 1);
                const int h2 = q & 1;
                *(ushort4_*)&agrp[tap * 512 + fswz(f) * 8 + h2 * 4] = v;
            }
            __syncthreads();

            bf16x8 af[9];
            #pragma unroll
            for (int kc = 0; kc < 9; ++kc) {
                u2b8 cvt;
                cvt.u = *(const ushort8*)&agrp[kc * 512 + afbase];
                af[kc] = cvt.b;
            }

            #pragma unroll
            for (int kc = 0; kc < 9; ++kc) {
                const int k2 = kc / 3, k3 = kc - 3 * (kc / 3);
                const int koff = (k2 * DP + k3) * CIN;
                #pragma unroll
                for (int t = 0; t < TPW; ++t) {
                    u2b8 cvt;
                    cvt.u = *(const ushort8*)&slab[sbase[t] + koff];
                    acc[t] = __builtin_amdgcn_mfma_f32_32x32x16_bf16(
                                 af[kc], cvt.b, acc[t], 0, 0, 0);
                }
            }
        }
    }

    float* ob = out + (long)b * COUT * D4_ + (long)d0 * D3_ + (long)d1 * D2_;
    #pragma unroll
    for (int t = 0; t < TPW; ++t) {
        #pragma unroll
        for (int r = 0; r < 16; ++r) {
            const int co = (r & 3) + 8 * (r >> 2) + 4 * hi;
            ob[(long)co * D4_ + ppos[t]] = acc[t][r];
        }
    }
}

extern "C" void kernel_launch(void* const* d_in, const int* in_sizes, int n_in,
                              void* d_out, int out_size, void* d_ws, size_t ws_size,
                              hipStream_t stream)
{
    const float* x = (const float*)d_in[0];
    const float* W = (const float*)d_in[1];
    float* out     = (float*)d_out;

    if (ws_size >= (size_t)WS_NEED) {
        // reset barrier counter every call (captured as a memset node)
        hipMemsetAsync((char*)d_ws + CNT_OFF_B, 0, 64, stream);
        hipLaunchKernelGGL(conv4d_fused, dim3(GRID), dim3(NTHR), 0, stream,
                           x, W, out, (ushort_t*)d_ws);
    } else {
        hipLaunchKernelGGL(conv4d_mfma_fb, dim3(D * D, 2), dim3(NTHR), 0, stream,
                           x, W, out);
    }
}